// Round 1
// baseline (16332.217 us; speedup 1.0000x reference)
//
#include <hip/hip_runtime.h>

// VanillaRNN on MI355X.
// Decomposition: 16 clusters (16 batch rows each) x 16 blocks (64 hidden outs each).
// Each block: 4 waves, K-split of the 1280-long dot (1024 h-part + 256 x-part folded in).
// W' = [W_hh | W_hx] slice lives in VGPRs for all 512 steps (160 VGPR/lane, bf16 frags).
// h handoff between blocks of a cluster: global double-buffer, packed in MFMA A-frag
// order, flag-based spin sync with agent-scope fences (XCD-safe).

typedef __attribute__((ext_vector_type(8))) short short8;
typedef __attribute__((ext_vector_type(4))) float f32x4;
typedef __attribute__((ext_vector_type(4))) unsigned short u16x4;
typedef unsigned short u16;

#define MF(A, B, C) (C) = __builtin_amdgcn_mfma_f32_16x16x32_bf16((A), (B), (C), 0, 0, 0)

// ---- workspace layout (bytes) ----
#define XPACK_OFF   0UL           // 16g * 512t * 8c * 64l * 16B = 67108864
#define WPACK_OFF   67108864UL    // 2560 frags * 1024B         = 2621440
#define WHOP_OFF    69730304UL    // 256 frags * 1024B          = 262144
#define HGLOB_OFF   69992448UL    // 16g * 2buf * 32KB          = 1048576
#define FLAGS_OFF   71041024UL    // 512*16 ints                = 32768
// total 71073792 bytes

__device__ __forceinline__ u16 f2bf(float f) {
  union { float f; unsigned u; } v; v.f = f;
  unsigned r = v.u + 0x7FFFu + ((v.u >> 16) & 1u);   // RNE
  return (u16)(r >> 16);
}

__device__ __forceinline__ float tanh_fast(float x) {
  float cx = fminf(10.f, fmaxf(-10.f, x));
  float e = __expf(2.f * cx);
  return (e - 1.f) / (e + 1.f);
}

// Fragment k-map (used identically for A-side and B-side packs; any bijection works
// as long as both sides agree): within a 32-k chunk, lane l elem j -> k = 8*(l>>4)+j.

__global__ __launch_bounds__(256) void zero_flags_kernel(int* __restrict__ f) {
  f[blockIdx.x * 256 + threadIdx.x] = 0;
}

// x [256b][512t][256k] fp32 -> xpack bf16 frags [g][t][c(8)][lane(64)][j(8)]
__global__ __launch_bounds__(256) void pack_x_kernel(const float* __restrict__ x, u16* __restrict__ xpack) {
  const int l = threadIdx.x & 63;
  const int rib = threadIdx.x >> 6;
  const long bt = (long)blockIdx.x * 4 + rib;   // b*512 + t
  const int b = (int)(bt >> 9);
  const int t = (int)(bt & 511);
  const f32x4 xv = *(const f32x4*)(x + bt * 256 + l * 4);
  const int k = l * 4;
  const int g = b >> 4;
  const int c = k >> 5;
  const int lt = ((k >> 3) & 3) * 16 + (b & 15);
  const int j = k & 7;
  u16x4 o;
  o[0] = f2bf(xv[0]); o[1] = f2bf(xv[1]); o[2] = f2bf(xv[2]); o[3] = f2bf(xv[3]);
  const long idx = ((((long)g * 512 + t) * 8 + c) * 64 + lt) * 8 + j;
  *(u16x4*)(xpack + idx) = o;
}

// W_hh[1024][1024], W_hx[1024][256] -> wpack frags [(s*4+w)*10+kc][nt][lane][8]
// W_ho[128][1024] -> whop frags [nt*32+c][lane][8]
__global__ __launch_bounds__(256) void pack_w_kernel(const float* __restrict__ Whh, const float* __restrict__ Whx,
                                                     const float* __restrict__ Who, u16* __restrict__ wpack,
                                                     u16* __restrict__ whop) {
  const int fid = blockIdx.x * 256 + threadIdx.x;
  const int l = fid & 63;
  const int frag = fid >> 6;
  const float* src;
  u16* dst;
  if (frag < 2560) {
    const int nt = frag & 3;
    const int kc = (frag >> 2) % 10;
    const int sw = frag / 40;          // s*4 + w
    const int w = sw & 3, s = sw >> 2;
    const int n = s * 64 + nt * 16 + (l & 15);
    if (kc < 8) src = Whh + n * 1024 + 32 * (8 * w + kc) + 8 * (l >> 4);
    else        src = Whx + n * 256  + 32 * (2 * w + kc - 8) + 8 * (l >> 4);
    dst = wpack + ((long)frag * 64 + l) * 8;
  } else if (frag < 2816) {
    const int f2 = frag - 2560;
    const int c = f2 & 31, nt = f2 >> 5;
    const int o = nt * 16 + (l & 15);
    src = Who + o * 1024 + 32 * c + 8 * (l >> 4);
    dst = whop + ((long)f2 * 64 + l) * 8;
  } else {
    return;
  }
  const f32x4 a = *(const f32x4*)src;
  const f32x4 b = *(const f32x4*)(src + 4);
  u16x4 o0, o1;
  o0[0] = f2bf(a[0]); o0[1] = f2bf(a[1]); o0[2] = f2bf(a[2]); o0[3] = f2bf(a[3]);
  o1[0] = f2bf(b[0]); o1[1] = f2bf(b[1]); o1[2] = f2bf(b[2]); o1[3] = f2bf(b[3]);
  *(u16x4*)dst = o0;
  *(u16x4*)(dst + 4) = o1;
}

extern "C" __global__ __launch_bounds__(256, 1) void rnn_main(
    const short8* __restrict__ xpack, const short8* __restrict__ wpack,
    const short8* __restrict__ whop, const float* __restrict__ bhx,
    const float* __restrict__ bho, u16* __restrict__ hglob,
    int* __restrict__ flags, float* __restrict__ out) {
  __shared__ f32x4 red_lds[16 * 64];   // 16KB: cross-wave K-partial reduction
  extern __shared__ f32x4 red2[];      // dynamic pad (occupancy limiter) + final-phase scratch

  const int tid = threadIdx.x;
  const int w = tid >> 6;              // wave id = K-slice id = owned out-tile id
  const int l = tid & 63;
  const int lr = l & 15, lgp = l >> 4;
  const int bid = blockIdx.x;
  const int g = bid & 15;              // cluster (batch group); same XCD under %8 round-robin
  const int s = bid >> 4;              // 64-out slice within cluster

  // --- load W' fragments into registers, once (40 x short8 = 160 VGPR/lane) ---
  short8 wreg[10][4];
  {
    const short8* wp = wpack + (long)(s * 4 + w) * 10 * 4 * 64;
#pragma unroll
    for (int kc = 0; kc < 10; kc++)
#pragma unroll
      for (int nt = 0; nt < 4; nt++)
        wreg[kc][nt] = wp[(kc * 4 + nt) * 64 + l];
  }
  const float bias = bhx[s * 64 + w * 16 + lr];
  const int n = s * 64 + w * 16 + lr;            // out index this lane stores
  const int cst = n >> 5, ltb = ((n >> 3) & 3) * 16, jst = n & 7;

#pragma unroll 1
  for (int t = 0; t < 512; ++t) {
    // x-part A-frags for this step (K-slice of wave w: chunks 2w, 2w+1)
    const short8* xp = xpack + (long)(g * 512 + t) * 8 * 64;
    short8 xa0 = xp[(2 * w + 0) * 64 + l];
    short8 xa1 = xp[(2 * w + 1) * 64 + l];

    f32x4 acc0 = {0.f, 0.f, 0.f, 0.f};
    f32x4 acc1 = acc0, acc2 = acc0, acc3 = acc0;

    MF(xa0, wreg[8][0], acc0); MF(xa0, wreg[8][1], acc1);
    MF(xa0, wreg[8][2], acc2); MF(xa0, wreg[8][3], acc3);
    MF(xa1, wreg[9][0], acc0); MF(xa1, wreg[9][1], acc1);
    MF(xa1, wreg[9][2], acc2); MF(xa1, wreg[9][3], acc3);

    if (t > 0) {
      // wait for all 64 waves of the cluster to have published h_t
      if (l == 0) {
        const int fi = (t - 1) * 16 + g;
        while (__hip_atomic_load(&flags[fi], __ATOMIC_RELAXED, __HIP_MEMORY_SCOPE_AGENT) < 64)
          __builtin_amdgcn_s_sleep(1);
      }
      __builtin_amdgcn_fence(__ATOMIC_ACQUIRE, "agent");
      const short8* hb = (const short8*)(hglob + (long)(g * 2 + (t & 1)) * 16384);
      short8 ha[8];
#pragma unroll
      for (int i = 0; i < 8; i++) ha[i] = hb[(w * 8 + i) * 64 + l];
#pragma unroll
      for (int i = 0; i < 8; i++) {
        MF(ha[i], wreg[i][0], acc0);
        MF(ha[i], wreg[i][1], acc1);
        MF(ha[i], wreg[i][2], acc2);
        MF(ha[i], wreg[i][3], acc3);
      }
    }

    // cross-wave reduction of K-partials: wave w keeps out-tile nt == w
    red_lds[(w * 4 + 0) * 64 + l] = acc0;
    red_lds[(w * 4 + 1) * 64 + l] = acc1;
    red_lds[(w * 4 + 2) * 64 + l] = acc2;
    red_lds[(w * 4 + 3) * 64 + l] = acc3;
    __syncthreads();
    f32x4 ssum = red_lds[(0 + w) * 64 + l] + red_lds[(4 + w) * 64 + l] +
                 red_lds[(8 + w) * 64 + l] + red_lds[(12 + w) * 64 + l];

    // epilogue: bias + tanh, store h_{t+1} packed in A-frag order
    u16* dst = hglob + (long)(g * 2 + ((t + 1) & 1)) * 16384;
#pragma unroll
    for (int r = 0; r < 4; r++) {
      float v = tanh_fast(ssum[r] + bias);
      dst[(cst * 64 + ltb + 4 * lgp + r) * 8 + jst] = f2bf(v);
    }
    __builtin_amdgcn_fence(__ATOMIC_RELEASE, "agent");
    if (l == 0)
      __hip_atomic_fetch_add(&flags[t * 16 + g], 1, __ATOMIC_RELAXED, __HIP_MEMORY_SCOPE_AGENT);
  }

  // ---- final: logits + softmax, one block (s==0) per cluster ----
  if (s != 0) return;
  if (l == 0) {
    while (__hip_atomic_load(&flags[511 * 16 + g], __ATOMIC_RELAXED, __HIP_MEMORY_SCOPE_AGENT) < 64)
      __builtin_amdgcn_s_sleep(1);
  }
  __builtin_amdgcn_fence(__ATOMIC_ACQUIRE, "agent");

  const short8* hb = (const short8*)(hglob + (long)(g * 2 + 0) * 16384);  // h_512 in buf 0
  f32x4 oa[8] = {};
#pragma unroll
  for (int i = 0; i < 8; i++) {
    short8 ha = hb[(w * 8 + i) * 64 + l];
#pragma unroll
    for (int nt = 0; nt < 8; nt++)
      MF(ha, whop[(nt * 32 + w * 8 + i) * 64 + l], oa[nt]);
  }
#pragma unroll
  for (int nt = 0; nt < 8; nt++) red2[(w * 8 + nt) * 64 + l] = oa[nt];
  __syncthreads();
#pragma unroll
  for (int q = 0; q < 2; q++) {
    const int nt = 2 * w + q;
    f32x4 lq = red2[(0 + nt) * 64 + l] + red2[(8 + nt) * 64 + l] +
               red2[(16 + nt) * 64 + l] + red2[(24 + nt) * 64 + l];
    const float bo = bho[nt * 16 + lr];
    lq[0] += bo; lq[1] += bo; lq[2] += bo; lq[3] += bo;
    red_lds[nt * 64 + l] = lq;
  }
  __syncthreads();
  if (w == 0) {
    const int b = l >> 2, q = l & 3;   // 16 rows x 4 lane-groups (32 cols each)
    const float* redf = (const float*)red_lds;
    float vv[32];
    float mx = -3.0e38f;
#pragma unroll
    for (int jj = 0; jj < 32; jj++) {
      const int o = q * 32 + jj;
      const int nt = o >> 4, m = o & 15;
      const float lv = redf[(nt * 64 + (b >> 2) * 16 + m) * 4 + (b & 3)];
      vv[jj] = lv;
      mx = fmaxf(mx, lv);
    }
    mx = fmaxf(mx, __shfl_xor(mx, 1));
    mx = fmaxf(mx, __shfl_xor(mx, 2));
    float se = 0.f;
#pragma unroll
    for (int jj = 0; jj < 32; jj++) { float e = __expf(vv[jj] - mx); vv[jj] = e; se += e; }
    se += __shfl_xor(se, 1);
    se += __shfl_xor(se, 2);
    const float inv = 1.f / se;
#pragma unroll
    for (int jj = 0; jj < 32; jj++)
      out[(g * 16 + b) * 128 + q * 32 + jj] = vv[jj] * inv;
  }
}

extern "C" void kernel_launch(void* const* d_in, const int* in_sizes, int n_in,
                              void* d_out, int out_size, void* d_ws, size_t ws_size,
                              hipStream_t stream) {
  const float* x   = (const float*)d_in[0];
  const float* Whx = (const float*)d_in[1];
  const float* bhx = (const float*)d_in[2];
  const float* Whh = (const float*)d_in[3];
  const float* Who = (const float*)d_in[4];
  const float* bho = (const float*)d_in[5];
  float* out = (float*)d_out;
  char* ws = (char*)d_ws;

  u16* xpack = (u16*)(ws + XPACK_OFF);
  u16* wpack = (u16*)(ws + WPACK_OFF);
  u16* whop  = (u16*)(ws + WHOP_OFF);
  u16* hglob = (u16*)(ws + HGLOB_OFF);
  int* flags = (int*)(ws + FLAGS_OFF);

  zero_flags_kernel<<<32, 256, 0, stream>>>(flags);
  pack_x_kernel<<<32768, 256, 0, stream>>>(x, xpack);
  pack_w_kernel<<<704, 256, 0, stream>>>(Whh, Whx, Who, wpack, whop);

  // LDS pad: static 16KB + dynamic 72KB = 88KB -> exactly 1 block/CU (spin-sync safe,
  // 256 blocks on 256 CUs). Fall back to 48KB dynamic if >64KB opt-in is unavailable.
  size_t dynsz = 73728;
  if (hipFuncSetAttribute((const void*)rnn_main,
                          hipFuncAttributeMaxDynamicSharedMemorySize, 73728) != hipSuccess)
    dynsz = 49152;

  rnn_main<<<256, 256, dynsz, stream>>>((const short8*)xpack, (const short8*)wpack,
                                        (const short8*)whop, bhx, bho, hglob, flags, out);
}

// Round 3
// 1296.090 us; speedup vs baseline: 12.6011x; 12.6011x over previous
//
#include <hip/hip_runtime.h>

// VanillaRNN on MI355X — round 3: fence-free cross-block sync (round-2 scheme)
// with the h-load indexing typo fixed (per-lane offset `l` was dropped).
// 16 clusters (16 batch rows) x 16 blocks (64 hidden outs). W' = [W_hh|W_hx]
// slice persists in VGPRs all 512 steps. h handoff via MALL-coherent relaxed
// agent-scope atomics (sc1 cache-bypass) + per-block padded flag counters.
// NO agent acquire/release fences in the hot loop (they emit buffer_inv /
// L2 writebacks costing ~30us/step — round-1 lesson).

typedef __attribute__((ext_vector_type(8))) short short8;
typedef __attribute__((ext_vector_type(4))) float f32x4;
typedef __attribute__((ext_vector_type(4))) unsigned short u16x4;
typedef unsigned short u16;
typedef unsigned long long u64;

#define MF(A, B, C) (C) = __builtin_amdgcn_mfma_f32_16x16x32_bf16((A), (B), (C), 0, 0, 0)

// ---- workspace layout (bytes) ----
#define XPACK_OFF   0UL           // 16g * 512t * 8c * 64l * 16B = 67108864
#define WPACK_OFF   67108864UL    // 2560 frags * 1024B         = 2621440
#define WHOP_OFF    69730304UL    // 256 frags * 1024B          = 262144
#define HGLOB_OFF   69992448UL    // 16g * 2buf * 32KB          = 1048576
#define FLAGS_OFF   71041024UL    // 512*16 * 128B              = 1048576
// total 72089600 bytes

__device__ __forceinline__ u16 f2bf(float f) {
  union { float f; unsigned u; } v; v.f = f;
  unsigned r = v.u + 0x7FFFu + ((v.u >> 16) & 1u);   // RNE
  return (u16)(r >> 16);
}

__device__ __forceinline__ float tanh_fast(float x) {
  float cx = fminf(10.f, fmaxf(-10.f, x));
  float e = __expf(2.f * cx);
  return (e - 1.f) / (e + 1.f);
}

__global__ __launch_bounds__(256) void zero_flags_kernel(int* __restrict__ f) {
  f[blockIdx.x * 256 + threadIdx.x] = 0;
}

// x [256b][512t][256k] fp32 -> xpack bf16 frags [g][t][c(8)][lane(64)][j(8)]
__global__ __launch_bounds__(256) void pack_x_kernel(const float* __restrict__ x, u16* __restrict__ xpack) {
  const int l = threadIdx.x & 63;
  const int rib = threadIdx.x >> 6;
  const long bt = (long)blockIdx.x * 4 + rib;   // b*512 + t
  const int b = (int)(bt >> 9);
  const int t = (int)(bt & 511);
  const f32x4 xv = *(const f32x4*)(x + bt * 256 + l * 4);
  const int k = l * 4;
  const int g = b >> 4;
  const int c = k >> 5;
  const int lt = ((k >> 3) & 3) * 16 + (b & 15);
  const int j = k & 7;
  u16x4 o;
  o[0] = f2bf(xv[0]); o[1] = f2bf(xv[1]); o[2] = f2bf(xv[2]); o[3] = f2bf(xv[3]);
  const long idx = ((((long)g * 512 + t) * 8 + c) * 64 + lt) * 8 + j;
  *(u16x4*)(xpack + idx) = o;
}

// W_hh[1024][1024], W_hx[1024][256] -> wpack frags [(s*4+w)*10+kc][nt][lane][8]
// W_ho[128][1024] -> whop frags [nt*32+c][lane][8]
__global__ __launch_bounds__(256) void pack_w_kernel(const float* __restrict__ Whh, const float* __restrict__ Whx,
                                                     const float* __restrict__ Who, u16* __restrict__ wpack,
                                                     u16* __restrict__ whop) {
  const int fid = blockIdx.x * 256 + threadIdx.x;
  const int l = fid & 63;
  const int frag = fid >> 6;
  const float* src;
  u16* dst;
  if (frag < 2560) {
    const int nt = frag & 3;
    const int kc = (frag >> 2) % 10;
    const int sw = frag / 40;          // s*4 + w
    const int w = sw & 3, s = sw >> 2;
    const int n = s * 64 + nt * 16 + (l & 15);
    if (kc < 8) src = Whh + n * 1024 + 32 * (8 * w + kc) + 8 * (l >> 4);
    else        src = Whx + n * 256  + 32 * (2 * w + kc - 8) + 8 * (l >> 4);
    dst = wpack + ((long)frag * 64 + l) * 8;
  } else if (frag < 2816) {
    const int f2 = frag - 2560;
    const int c = f2 & 31, nt = f2 >> 5;
    const int o = nt * 16 + (l & 15);
    src = Who + o * 1024 + 32 * c + 8 * (l >> 4);
    dst = whop + ((long)f2 * 64 + l) * 8;
  } else {
    return;
  }
  const f32x4 a = *(const f32x4*)src;
  const f32x4 b = *(const f32x4*)(src + 4);
  u16x4 o0, o1;
  o0[0] = f2bf(a[0]); o0[1] = f2bf(a[1]); o0[2] = f2bf(a[2]); o0[3] = f2bf(a[3]);
  o1[0] = f2bf(b[0]); o1[1] = f2bf(b[1]); o1[2] = f2bf(b[2]); o1[3] = f2bf(b[3]);
  *(u16x4*)dst = o0;
  *(u16x4*)(dst + 4) = o1;
}

extern "C" __global__ __launch_bounds__(256, 1) void rnn_main(
    const short8* __restrict__ xpack, const short8* __restrict__ wpack,
    const short8* __restrict__ whop, const float* __restrict__ bhx,
    const float* __restrict__ bho, u16* __restrict__ hglob,
    int* __restrict__ flags, float* __restrict__ out) {
  __shared__ f32x4 red_lds[16 * 64];   // 16KB: cross-wave K-partial reduction
  extern __shared__ f32x4 red2[];      // dynamic pad (occupancy limiter) + final-phase scratch

  const int tid = threadIdx.x;
  const int w = tid >> 6;              // wave id = K-slice id = owned out-tile id
  const int l = tid & 63;
  const int lr = l & 15, lgp = l >> 4;
  const int bid = blockIdx.x;
  const int g = bid & 15;              // cluster (batch group)
  const int s = bid >> 4;              // 64-out slice within cluster

  // --- load W' fragments into registers, once (40 x short8 = 160 regs/lane) ---
  short8 wreg[10][4];
  {
    const short8* wp = wpack + (long)(s * 4 + w) * 10 * 4 * 64;
#pragma unroll
    for (int kc = 0; kc < 10; kc++)
#pragma unroll
      for (int nt = 0; nt < 4; nt++)
        wreg[kc][nt] = wp[(kc * 4 + nt) * 64 + l];
  }
  const float bias = bhx[s * 64 + w * 16 + lr];
  const int n = s * 64 + w * 16 + lr;            // out index this lane stores
  const int cst = n >> 5, ltb = ((n >> 3) & 3) * 16, jst = n & 7;

#pragma unroll 1
  for (int t = 0; t < 512; ++t) {
    // x-part A-frags (plain cached loads; read-only data, no coherence issue)
    const short8* xp = xpack + (long)(g * 512 + t) * 8 * 64;
    short8 xa0 = xp[(2 * w + 0) * 64 + l];
    short8 xa1 = xp[(2 * w + 1) * 64 + l];

    f32x4 acc0 = {0.f, 0.f, 0.f, 0.f};
    f32x4 acc1 = acc0, acc2 = acc0, acc3 = acc0;

    MF(xa0, wreg[8][0], acc0); MF(xa0, wreg[8][1], acc1);
    MF(xa0, wreg[8][2], acc2); MF(xa0, wreg[8][3], acc3);
    MF(xa1, wreg[9][0], acc0); MF(xa1, wreg[9][1], acc1);
    MF(xa1, wreg[9][2], acc2); MF(xa1, wreg[9][3], acc3);

    if (t > 0) {
      // wait until all 16 blocks of this cluster have published h_t
      const int* fp = flags + (size_t)((t - 1) * 16 + g) * 32;
      int v = __hip_atomic_load(fp, __ATOMIC_RELAXED, __HIP_MEMORY_SCOPE_AGENT);
      while (v < 16) {
        __builtin_amdgcn_s_sleep(1);
        v = __hip_atomic_load(fp, __ATOMIC_RELAXED, __HIP_MEMORY_SCOPE_AGENT);
      }
      // unbreakable dependency: h loads can't be hoisted above the poll
      unsigned dep = 0;
      asm volatile("" : "+v"(dep) : "v"(v));
      const u64* hq = (const u64*)(hglob + (size_t)(g * 2 + (t & 1)) * 16384) + dep;
      short8 ha[8];
#pragma unroll
      for (int i = 0; i < 8; i++) {
        union { u64 q[2]; short8 v8; } hu;
        const size_t qi = ((size_t)(w * 8 + i) * 64 + l) * 2;   // per-lane offset l restored
        hu.q[0] = __hip_atomic_load(hq + qi + 0, __ATOMIC_RELAXED, __HIP_MEMORY_SCOPE_AGENT);
        hu.q[1] = __hip_atomic_load(hq + qi + 1, __ATOMIC_RELAXED, __HIP_MEMORY_SCOPE_AGENT);
        ha[i] = hu.v8;
      }
#pragma unroll
      for (int i = 0; i < 8; i++) {
        MF(ha[i], wreg[i][0], acc0);
        MF(ha[i], wreg[i][1], acc1);
        MF(ha[i], wreg[i][2], acc2);
        MF(ha[i], wreg[i][3], acc3);
      }
    }

    // cross-wave reduction of K-partials: wave w keeps out-tile nt == w
    red_lds[(w * 4 + 0) * 64 + l] = acc0;
    red_lds[(w * 4 + 1) * 64 + l] = acc1;
    red_lds[(w * 4 + 2) * 64 + l] = acc2;
    red_lds[(w * 4 + 3) * 64 + l] = acc3;
    __syncthreads();
    f32x4 ssum = red_lds[(0 + w) * 64 + l] + red_lds[(4 + w) * 64 + l] +
                 red_lds[(8 + w) * 64 + l] + red_lds[(12 + w) * 64 + l];

    // epilogue: bias + tanh, publish h_{t+1} (cache-bypass stores, MALL-coherent)
    u16* dst = hglob + (size_t)(g * 2 + ((t + 1) & 1)) * 16384;
#pragma unroll
    for (int r = 0; r < 4; r++) {
      float hv = tanh_fast(ssum[r] + bias);
      __hip_atomic_store(dst + (size_t)(cst * 64 + ltb + 4 * lgp + r) * 8 + jst,
                         f2bf(hv), __ATOMIC_RELAXED, __HIP_MEMORY_SCOPE_AGENT);
    }
    // drain this wave's stores (vmcnt) + block barrier; NO cache maintenance
    __builtin_amdgcn_fence(__ATOMIC_RELEASE, "workgroup");
    __syncthreads();
    if (tid == 0)
      __hip_atomic_fetch_add(flags + (size_t)(t * 16 + g) * 32, 1,
                             __ATOMIC_RELAXED, __HIP_MEMORY_SCOPE_AGENT);
  }

  // ---- final: logits + softmax, one block (s==0) per cluster ----
  if (s != 0) return;
  {
    const int* fp = flags + (size_t)(511 * 16 + g) * 32;
    int v = __hip_atomic_load(fp, __ATOMIC_RELAXED, __HIP_MEMORY_SCOPE_AGENT);
    while (v < 16) {
      __builtin_amdgcn_s_sleep(1);
      v = __hip_atomic_load(fp, __ATOMIC_RELAXED, __HIP_MEMORY_SCOPE_AGENT);
    }
    unsigned dep = 0;
    asm volatile("" : "+v"(dep) : "v"(v));
    const u64* hq = (const u64*)(hglob + (size_t)(g * 2 + 0) * 16384) + dep;  // h_512 in buf 0
    f32x4 oa[8] = {};
#pragma unroll
    for (int i = 0; i < 8; i++) {
      union { u64 q[2]; short8 v8; } hu;
      const size_t qi = ((size_t)(w * 8 + i) * 64 + l) * 2;     // per-lane offset l restored
      hu.q[0] = __hip_atomic_load(hq + qi + 0, __ATOMIC_RELAXED, __HIP_MEMORY_SCOPE_AGENT);
      hu.q[1] = __hip_atomic_load(hq + qi + 1, __ATOMIC_RELAXED, __HIP_MEMORY_SCOPE_AGENT);
      short8 ha = hu.v8;
#pragma unroll
      for (int nt = 0; nt < 8; nt++)
        MF(ha, whop[(nt * 32 + w * 8 + i) * 64 + l], oa[nt]);
    }
#pragma unroll
    for (int nt = 0; nt < 8; nt++) red2[(w * 8 + nt) * 64 + l] = oa[nt];
  }
  __syncthreads();
#pragma unroll
  for (int q = 0; q < 2; q++) {
    const int nt = 2 * w + q;
    f32x4 lq = red2[(0 + nt) * 64 + l] + red2[(8 + nt) * 64 + l] +
               red2[(16 + nt) * 64 + l] + red2[(24 + nt) * 64 + l];
    const float bo = bho[nt * 16 + lr];
    lq[0] += bo; lq[1] += bo; lq[2] += bo; lq[3] += bo;
    red_lds[nt * 64 + l] = lq;
  }
  __syncthreads();
  if (w == 0) {
    const int b = l >> 2, q = l & 3;   // 16 rows x 4 lane-groups (32 cols each)
    const float* redf = (const float*)red_lds;
    float vv[32];
    float mx = -3.0e38f;
#pragma unroll
    for (int jj = 0; jj < 32; jj++) {
      const int o = q * 32 + jj;
      const int nt = o >> 4, m = o & 15;
      const float lv = redf[(nt * 64 + (b >> 2) * 16 + m) * 4 + (b & 3)];
      vv[jj] = lv;
      mx = fmaxf(mx, lv);
    }
    mx = fmaxf(mx, __shfl_xor(mx, 1));
    mx = fmaxf(mx, __shfl_xor(mx, 2));
    float se = 0.f;
#pragma unroll
    for (int jj = 0; jj < 32; jj++) { float e = __expf(vv[jj] - mx); vv[jj] = e; se += e; }
    se += __shfl_xor(se, 1);
    se += __shfl_xor(se, 2);
    const float inv = 1.f / se;
#pragma unroll
    for (int jj = 0; jj < 32; jj++)
      out[(g * 16 + b) * 128 + q * 32 + jj] = vv[jj] * inv;
  }
}

extern "C" void kernel_launch(void* const* d_in, const int* in_sizes, int n_in,
                              void* d_out, int out_size, void* d_ws, size_t ws_size,
                              hipStream_t stream) {
  const float* x   = (const float*)d_in[0];
  const float* Whx = (const float*)d_in[1];
  const float* bhx = (const float*)d_in[2];
  const float* Whh = (const float*)d_in[3];
  const float* Who = (const float*)d_in[4];
  const float* bho = (const float*)d_in[5];
  float* out = (float*)d_out;
  char* ws = (char*)d_ws;

  u16* xpack = (u16*)(ws + XPACK_OFF);
  u16* wpack = (u16*)(ws + WPACK_OFF);
  u16* whop  = (u16*)(ws + WHOP_OFF);
  u16* hglob = (u16*)(ws + HGLOB_OFF);
  int* flags = (int*)(ws + FLAGS_OFF);

  zero_flags_kernel<<<1024, 256, 0, stream>>>(flags);
  pack_x_kernel<<<32768, 256, 0, stream>>>(x, xpack);
  pack_w_kernel<<<704, 256, 0, stream>>>(Whh, Whx, Who, wpack, whop);

  // LDS pad: static 16KB + dynamic 72KB = 88KB -> exactly 1 block/CU (spin-sync safe,
  // 256 blocks on 256 CUs). Fall back to 48KB dynamic if >64KB opt-in is unavailable.
  size_t dynsz = 73728;
  if (hipFuncSetAttribute((const void*)rnn_main,
                          hipFuncAttributeMaxDynamicSharedMemorySize, 73728) != hipSuccess)
    dynsz = 49152;

  rnn_main<<<256, 256, dynsz, stream>>>((const short8*)xpack, (const short8*)wpack,
                                        (const short8*)whop, bhx, bho, hglob, flags, out);
}